// Round 7
// baseline (137.575 us; speedup 1.0000x reference)
//
#include <hip/hip_runtime.h>
#include <hip/hip_cooperative_groups.h>

namespace cg = cooperative_groups;

// LaplacianLossBatch: B=16, NV=2562, NF=5120
// Exact reference semantics (verified: absmax 0.0 in R1-R6):
//   A[i,j] = 1 iff pair (i,j) set by any face (6 ordered pairs/face, SET semantics)
//   deg[i] = popcount(row i of A)  (diagonal bit included — degenerate faces)
//   v_avg[i] = deg>0 ? v[i] - (sum_{j!=i, A[i,j]} v[j]) / deg : 0
//   out = sum(v_avg^2)
//
// R5: fused LDS-tiled kernel + reduce kernel (30.0us).
// R6: 16-lanes-per-row phase 2 (24->4 shuffles/row), float2 staging (18.9us).
// R7: single COOPERATIVE kernel — grid.sync + block(0,0) reduction removes
//     the second dispatch (~3-4us of graph chain); int4 face loads (4 faces
//     per 3 dwordx4) cut phase-1 load issue 3-4x.
//     Co-residency: LDS 51.5KB -> 3 blocks/CU -> 768 >= 656 blocks.

constexpr int NV = 2562;
constexpr int NF = 5120;
constexpr int BATCH = 16;
constexpr int W = (NV + 31) / 32;            // 81 words per bitmask row
constexpr int TILE = 64;                     // rows per block
constexpr int NT = (NV + TILE - 1) / TILE;   // 41 tiles (last tile: 2 rows)
constexpr int THREADS = 512;                 // 8 waves
constexpr int NPART = NT * BATCH;            // 656 partials

__global__ __launch_bounds__(THREADS, 6)     // 6 waves/SIMD -> VGPR capped, 3 blocks/CU
void lap_fused_coop(const float* __restrict__ vertices,
                    const int* __restrict__ faces,
                    float* __restrict__ partial,
                    float* __restrict__ out) {
    __shared__ unsigned int m[TILE * W];             // 20736 B
    __shared__ __align__(16) float vsh[NV * 3];      // 30744 B
    __shared__ float red[THREADS / 64];

    const int tile = blockIdx.x;
    const int b    = blockIdx.y;
    const int v0   = tile * TILE;
    const int tid  = threadIdx.x;

    // phase 0: clear LDS mask + stage this batch's vertices (float2-aligned)
    for (int k = tid; k < TILE * W; k += THREADS) m[k] = 0u;
    const float2* vb2 = (const float2*)(vertices + (size_t)b * NV * 3);
    float2* vsh2 = (float2*)vsh;
    constexpr int NV3_2 = (NV * 3) / 2;              // 3843 float2, exact
    for (int k = tid; k < NV3_2; k += THREADS) vsh2[k] = vb2[k];
    __syncthreads();

    // phase 1: int4 face loads — 3 dwordx4 = 4 faces. Per-batch base is
    // b*61440 bytes: 16B-aligned. Indices fully unrolled -> static (no scratch).
    const int4* fb4 = (const int4*)(faces + (size_t)b * NF * 3);
    constexpr int NQ = NF / 4;                       // 1280 face-quads
    for (int q = tid; q < NQ; q += THREADS) {
        int4 a = fb4[3 * q], c = fb4[3 * q + 1], d = fb4[3 * q + 2];
        const int v[12] = {a.x, a.y, a.z, a.w, c.x, c.y, c.z, c.w,
                           d.x, d.y, d.z, d.w};
        auto setb = [&](int s, int dd) {
            unsigned r = (unsigned)(s - v0);
            if (r < (unsigned)TILE)
                atomicOr(&m[r * W + (dd >> 5)], 1u << (dd & 31));
        };
        #pragma unroll
        for (int ff = 0; ff < 4; ++ff) {
            int i0 = v[3 * ff], i1 = v[3 * ff + 1], i2 = v[3 * ff + 2];
            setb(i0, i1); setb(i1, i0);
            setb(i1, i2); setb(i2, i1);
            setb(i2, i0); setb(i0, i2);
        }
    }
    __syncthreads();

    // phase 2: 4 rows per wave, 16 lanes per row; 2 passes cover 64 rows.
    const int lane = tid & 63;
    const int wid  = tid >> 6;
    const int g    = lane >> 4;      // row group within wave (0..3)
    const int s    = lane & 15;      // sublane within row group
    const int rows = min(TILE, NV - v0);
    float acc = 0.f;                 // nonzero only on s==0 lanes

    #pragma unroll
    for (int pass = 0; pass < TILE / 32; ++pass) {
        int r = pass * 32 + wid * 4 + g;
        float deg = 0.f, sx = 0.f, sy = 0.f, sz = 0.f;
        int i = v0 + r;
        if (r < rows) {
            const unsigned int* row = &m[r * W];
            for (int w = s; w < W; w += 16) {
                unsigned bits = row[w];
                deg += (float)__popc(bits);
                while (bits) {
                    int bno = __ffs(bits) - 1;
                    bits &= bits - 1;
                    int j = w * 32 + bno;
                    if (j != i) {    // diagonal in deg, not in neighbor sum
                        sx += vsh[3 * j];
                        sy += vsh[3 * j + 1];
                        sz += vsh[3 * j + 2];
                    }
                }
            }
        }
        // reduce within each 16-lane group (xor 1,2,4,8 stays in-group)
        #pragma unroll
        for (int off = 1; off <= 8; off <<= 1) {
            deg += __shfl_xor(deg, off);
            sx  += __shfl_xor(sx,  off);
            sy  += __shfl_xor(sy,  off);
            sz  += __shfl_xor(sz,  off);
        }
        if (s == 0 && r < rows && deg > 0.5f) {
            float inv = 1.f / deg;
            float ax = vsh[3 * i]     - sx * inv;
            float ay = vsh[3 * i + 1] - sy * inv;
            float az = vsh[3 * i + 2] - sz * inv;
            acc += ax * ax + ay * ay + az * az;
        }
    }
    acc += __shfl_xor(acc, 16);
    acc += __shfl_xor(acc, 32);
    if (lane == 0) red[wid] = acc;
    __syncthreads();
    if (tid == 0) {
        float t = 0.f;
        #pragma unroll
        for (int k = 0; k < THREADS / 64; ++k) t += red[k];
        partial[(size_t)b * NT + tile] = t;  // plain store: poison-immune
    }

    // grid-wide sync, then one block folds the 656 partials.
    __threadfence();                 // device-scope release (cross-XCD)
    cg::this_grid().sync();
    if (blockIdx.x == 0 && blockIdx.y == 0) {
        float local = 0.f;
        if (tid < NPART) local = partial[tid];
        if (tid + THREADS < NPART) local += partial[tid + THREADS];
        #pragma unroll
        for (int off = 32; off; off >>= 1) local += __shfl_down(local, off);
        if ((tid & 63) == 0) red[tid >> 6] = local;   // red reuse: grid.sync ordered
        __syncthreads();
        if (tid == 0) {
            float sum = 0.f;
            #pragma unroll
            for (int k = 0; k < THREADS / 64; ++k) sum += red[k];
            out[0] = sum;
        }
    }
}

extern "C" void kernel_launch(void* const* d_in, const int* in_sizes, int n_in,
                              void* d_out, int out_size, void* d_ws, size_t ws_size,
                              hipStream_t stream) {
    const float* vertices = (const float*)d_in[0];
    const int*   faces    = (const int*)d_in[1];
    float*       out      = (float*)d_out;
    float*       partial  = (float*)d_ws;    // 656 floats (2.6 KB)

    void* args[] = { (void*)&vertices, (void*)&faces, (void*)&partial, (void*)&out };
    dim3 grid(NT, BATCH), block(THREADS);
    hipLaunchCooperativeKernel((const void*)lap_fused_coop, grid, block,
                               args, 0, stream);
}

// Round 8
// 18.489 us; speedup vs baseline: 7.4410x; 7.4410x over previous
//
#include <hip/hip_runtime.h>

// LaplacianLossBatch: B=16, NV=2562, NF=5120
// Exact reference semantics (verified: absmax 0.0 in R1-R7):
//   A[i,j] = 1 iff pair (i,j) set by any face (6 ordered pairs/face, SET semantics)
//   deg[i] = popcount(row i of A)  (diagonal bit included — degenerate faces)
//   v_avg[i] = deg>0 ? v[i] - (sum_{j!=i, A[i,j]} v[j]) / deg : 0
//   out = sum(v_avg^2)
//
// R6: fused LDS-tiled kernel + reduce kernel, 16-lanes-per-row scan (18.9us).
// R7: cooperative single-kernel FAILED — cg::this_grid().sync() spun ~120us
//     across 8 non-coherent XCD L2s. Reverted.
// R8: R6 structure + (a) int4 face loads (3 dwordx4 = 4 faces, 3-4x fewer
//     load issues), (b) TILE=96 (61.9KB static LDS, 432 blocks @ 2/CU =
//     still one occupancy round; per-CU face-scan redundancy 2.56x -> 1.69x).

constexpr int NV = 2562;
constexpr int NF = 5120;
constexpr int BATCH = 16;
constexpr int W = (NV + 31) / 32;            // 81 words per bitmask row
constexpr int TILE = 96;                     // rows per block
constexpr int NT = (NV + TILE - 1) / TILE;   // 27 tiles (last tile: 66 rows)
constexpr int THREADS = 512;                 // 8 waves
constexpr int NPART = NT * BATCH;            // 432 partials

static_assert(TILE % 32 == 0, "phase-2 pass structure");
static_assert(TILE * W * 4 + NV * 3 * 4 + 32 < 64 * 1024, "static LDS limit");

__global__ __launch_bounds__(THREADS)
void lap_fused(const float* __restrict__ vertices,
               const int* __restrict__ faces,
               float* __restrict__ partial) {
    __shared__ unsigned int m[TILE * W];             // 31104 B
    __shared__ __align__(16) float vsh[NV * 3];      // 30744 B
    __shared__ float red[THREADS / 64];

    const int tile = blockIdx.x;
    const int b    = blockIdx.y;
    const int v0   = tile * TILE;
    const int tid  = threadIdx.x;

    // phase 0: clear LDS mask + stage this batch's vertices (float2: the
    // per-batch base (b*30744 bytes) is only 8B-aligned for odd b)
    for (int k = tid; k < TILE * W; k += THREADS) m[k] = 0u;
    const float2* vb2 = (const float2*)(vertices + (size_t)b * NV * 3);
    float2* vsh2 = (float2*)vsh;
    constexpr int NV3_2 = (NV * 3) / 2;              // 3843 float2, exact
    for (int k = tid; k < NV3_2; k += THREADS) vsh2[k] = vb2[k];
    __syncthreads();

    // phase 1: int4 face loads — 3 dwordx4 = 4 faces. Per-batch base is
    // b*61440 bytes: 16B-aligned. Indices fully unrolled -> static regs.
    const int4* fb4 = (const int4*)(faces + (size_t)b * NF * 3);
    constexpr int NQ = NF / 4;                       // 1280 face-quads
    for (int q = tid; q < NQ; q += THREADS) {
        int4 a = fb4[3 * q], c = fb4[3 * q + 1], d = fb4[3 * q + 2];
        const int v[12] = {a.x, a.y, a.z, a.w, c.x, c.y, c.z, c.w,
                           d.x, d.y, d.z, d.w};
        auto setb = [&](int s, int dd) {
            unsigned r = (unsigned)(s - v0);
            if (r < (unsigned)TILE)
                atomicOr(&m[r * W + (dd >> 5)], 1u << (dd & 31));
        };
        #pragma unroll
        for (int ff = 0; ff < 4; ++ff) {
            int i0 = v[3 * ff], i1 = v[3 * ff + 1], i2 = v[3 * ff + 2];
            setb(i0, i1); setb(i1, i0);
            setb(i1, i2); setb(i2, i1);
            setb(i2, i0); setb(i0, i2);
        }
    }
    __syncthreads();

    // phase 2: 4 rows per wave, 16 lanes per row; TILE/32 passes.
    const int lane = tid & 63;
    const int wid  = tid >> 6;
    const int g    = lane >> 4;      // row group within wave (0..3)
    const int s    = lane & 15;      // sublane within row group
    const int rows = min(TILE, NV - v0);
    float acc = 0.f;                 // nonzero only on s==0 lanes

    #pragma unroll
    for (int pass = 0; pass < TILE / 32; ++pass) {
        int r = pass * 32 + wid * 4 + g;
        float deg = 0.f, sx = 0.f, sy = 0.f, sz = 0.f;
        int i = v0 + r;
        if (r < rows) {
            const unsigned int* row = &m[r * W];
            for (int w = s; w < W; w += 16) {
                unsigned bits = row[w];
                deg += (float)__popc(bits);
                while (bits) {
                    int bno = __ffs(bits) - 1;
                    bits &= bits - 1;
                    int j = w * 32 + bno;
                    if (j != i) {    // diagonal in deg, not in neighbor sum
                        sx += vsh[3 * j];
                        sy += vsh[3 * j + 1];
                        sz += vsh[3 * j + 2];
                    }
                }
            }
        }
        // reduce within each 16-lane group (xor 1,2,4,8 stays in-group)
        #pragma unroll
        for (int off = 1; off <= 8; off <<= 1) {
            deg += __shfl_xor(deg, off);
            sx  += __shfl_xor(sx,  off);
            sy  += __shfl_xor(sy,  off);
            sz  += __shfl_xor(sz,  off);
        }
        if (s == 0 && r < rows && deg > 0.5f) {
            float inv = 1.f / deg;
            float ax = vsh[3 * i]     - sx * inv;
            float ay = vsh[3 * i + 1] - sy * inv;
            float az = vsh[3 * i + 2] - sz * inv;
            acc += ax * ax + ay * ay + az * az;
        }
    }
    // fold the 4 group-lanes (0,16,32,48); other lanes carry 0
    acc += __shfl_xor(acc, 16);
    acc += __shfl_xor(acc, 32);
    if (lane == 0) red[wid] = acc;
    __syncthreads();
    if (tid == 0) {
        float t = 0.f;
        #pragma unroll
        for (int k = 0; k < THREADS / 64; ++k) t += red[k];
        partial[(size_t)b * gridDim.x + tile] = t;   // plain store: poison-immune
    }
}

__global__ void lap_reduce(const float* __restrict__ partial, int n4,
                           float* __restrict__ out) {
    // n4 float4 elements (n4*4 floats, exact multiple by construction)
    const float4* p4 = (const float4*)partial;
    float local = 0.f;
    for (int k = threadIdx.x; k < n4; k += blockDim.x) {
        float4 v = p4[k];
        local += (v.x + v.y) + (v.z + v.w);
    }
    #pragma unroll
    for (int off = 32; off; off >>= 1) local += __shfl_down(local, off);
    __shared__ float red[4];
    int lane = threadIdx.x & 63, wid = threadIdx.x >> 6;
    if (lane == 0) red[wid] = local;
    __syncthreads();
    if (threadIdx.x == 0) out[0] = red[0] + red[1] + red[2] + red[3];
}

extern "C" void kernel_launch(void* const* d_in, const int* in_sizes, int n_in,
                              void* d_out, int out_size, void* d_ws, size_t ws_size,
                              hipStream_t stream) {
    const float* vertices = (const float*)d_in[0];
    const int*   faces    = (const int*)d_in[1];
    float*       out      = (float*)d_out;
    float*       partial  = (float*)d_ws;    // NPART = 432 floats (1.7 KB)

    lap_fused<<<dim3(NT, BATCH), THREADS, 0, stream>>>(vertices, faces, partial);
    static_assert(NPART % 4 == 0, "reduce uses float4");
    lap_reduce<<<1, 256, 0, stream>>>(partial, NPART / 4, out);
}